// Round 6
// baseline (67.555 us; speedup 1.0000x reference)
//
#include <hip/hip_runtime.h>

#define L_SEQ 1024
#define NB 8
#define NM 64
#define LM (L_SEQ * NM)    // 65536
#define BLM (NB * LM)      // 524288
#define RS8 0.35355339059327373f
#define LOG2E 1.4426950408889634f

typedef unsigned short u16;
typedef __attribute__((ext_vector_type(8))) short short8;
typedef __attribute__((ext_vector_type(4))) float f32x4;
typedef __attribute__((ext_vector_type(8))) u16 us8;

__device__ __forceinline__ float wredsum(float v) {
#pragma unroll
    for (int off = 32; off; off >>= 1) v += __shfl_xor(v, off);
    return v;
}

__device__ __forceinline__ u16 f2bf(float f) {
    unsigned int u = __float_as_uint(f);
    unsigned int r = (u + 0x7FFFu + ((u >> 16) & 1u)) >> 16;
    return (u16)r;
}

// ---------------- Prep: W fp32 -> bf16 (same layout); x[b][k][m] -> xT[b][m][k] bf16 ----------------
__global__ __launch_bounds__(256) void prep_kernel(
        const float* __restrict__ x, const float* __restrict__ Wq,
        const float* __restrict__ Wk, const float* __restrict__ Wv,
        u16* __restrict__ Wbf, u16* __restrict__ xT) {
    const int bx = blockIdx.x;
    const int tid = threadIdx.x;
    if (bx < 1536) {                       // W convert: 3 x 512 blocks x 2048 elements
        const int w = bx >> 9;
        const int blk = bx & 511;
        const float* W = (w == 0) ? Wq : (w == 1) ? Wk : Wv;
        const size_t base = (size_t)blk * 2048 + (size_t)tid * 8;
        float4 f0 = *(const float4*)&W[base];
        float4 f1 = *(const float4*)&W[base + 4];
        us8 o;
        o[0] = f2bf(f0.x); o[1] = f2bf(f0.y); o[2] = f2bf(f0.z); o[3] = f2bf(f0.w);
        o[4] = f2bf(f1.x); o[5] = f2bf(f1.y); o[6] = f2bf(f1.z); o[7] = f2bf(f1.w);
        *(us8*)&Wbf[(size_t)w * 1048576 + base] = o;
    } else {                               // x transpose: 128 blocks (b, ktile)
        const int blk = bx - 1536;
        const int b = blk >> 4, kt = blk & 15;
        __shared__ float T[64][65];
        const int r16 = tid >> 4, c4 = (tid & 15) * 4;
#pragma unroll
        for (int s = 0; s < 4; s++) {
            int r = r16 + s * 16;
            *(float4*)&T[r][c4] = *(const float4*)&x[((size_t)b * L_SEQ + kt * 64 + r) * NM + c4];
        }
        __syncthreads();
        const int m = tid >> 2;
#pragma unroll
        for (int s = 0; s < 2; s++) {
            int c = (tid & 3) * 2 + s;
            int k0 = c * 8;
            us8 o;
#pragma unroll
            for (int j = 0; j < 8; j++) o[j] = f2bf(T[k0 + j][m]);
            *(us8*)&xT[((size_t)b * NM + m) * L_SEQ + kt * 64 + k0] = o;
        }
    }
}

// ---------------- Projection via MFMA -> head-major fp32 H[w][b][c][seq][8] ----------------
__global__ __launch_bounds__(64) void proj_mfma(
        const u16* __restrict__ Wbf, const u16* __restrict__ xT,
        float* __restrict__ H) {
    const int it = blockIdx.x;   // 32 row tiles
    const int b  = blockIdx.y;   // 8
    const int w  = blockIdx.z;   // 3
    const int l  = threadIdx.x;

    __shared__ __align__(16) u16 Ab[2][2048];   // [32 rows][64 k] swizzled
    __shared__ __align__(16) u16 Bb[2][4096];   // [64 m][64 k] swizzled

    const u16* As = Wbf + (size_t)w * 1048576 + (size_t)(it * 32) * L_SEQ;
    const u16* Bs = xT + (size_t)b * (NM * L_SEQ);

    const int soff = (l >> 3) * L_SEQ + (((l & 7) ^ (l >> 3)) * 8);
    const int ldst = l * 8;

    f32x4 acc[2][4];
#pragma unroll
    for (int i = 0; i < 2; i++)
#pragma unroll
        for (int j = 0; j < 4; j++) acc[i][j] = (f32x4){0.f, 0.f, 0.f, 0.f};

    short8 ra[4], rb[8];

#define LOADT(kt)  do { \
    _Pragma("unroll") for (int t = 0; t < 4; t++) ra[t] = *(const short8*)&As[(size_t)t * 8192 + soff + (kt) * 64]; \
    _Pragma("unroll") for (int t = 0; t < 8; t++) rb[t] = *(const short8*)&Bs[(size_t)t * 8192 + soff + (kt) * 64]; \
} while (0)
#define WRITET(cur) do { \
    _Pragma("unroll") for (int t = 0; t < 4; t++) *(short8*)&Ab[cur][t * 512 + ldst] = ra[t]; \
    _Pragma("unroll") for (int t = 0; t < 8; t++) *(short8*)&Bb[cur][t * 512 + ldst] = rb[t]; \
} while (0)

    const int frow = l & 15;
    const int fg = l >> 4;
    const int lx = l & 7;

    LOADT(0);
    WRITET(0);
    LOADT(1);

    for (int kt = 0; kt < 16; ++kt) {
        const int cur = kt & 1;
        __syncthreads();
#pragma unroll
        for (int ks = 0; ks < 2; ++ks) {
            const int ch = ((ks * 4 + fg) ^ lx) * 8;
            short8 af0 = *(const short8*)&Ab[cur][frow * 64 + ch];
            short8 af1 = *(const short8*)&Ab[cur][(16 + frow) * 64 + ch];
#pragma unroll
            for (int cg = 0; cg < 4; ++cg) {
                short8 bf = *(const short8*)&Bb[cur][(cg * 16 + frow) * 64 + ch];
                acc[0][cg] = __builtin_amdgcn_mfma_f32_16x16x32_bf16(af0, bf, acc[0][cg], 0, 0, 0);
                acc[1][cg] = __builtin_amdgcn_mfma_f32_16x16x32_bf16(af1, bf, acc[1][cg], 0, 0, 0);
            }
        }
        if (kt < 15) {
            WRITET(cur ^ 1);
            if (kt < 14) LOADT(kt + 2);
        }
    }

    // head-major fp32 store: H[w][b][c][i][d], c = m>>3, d = m&7
    float* dst = H + (size_t)w * 524288 + (size_t)b * 65536;
#pragma unroll
    for (int rg = 0; rg < 2; ++rg)
#pragma unroll
        for (int cg = 0; cg < 4; ++cg) {
            const int m = cg * 16 + frow;
            const int cc = m >> 3, d = m & 7;
#pragma unroll
            for (int r = 0; r < 4; ++r) {
                const int iq = it * 32 + rg * 16 + fg * 4 + r;
                dst[((size_t)cc * L_SEQ + iq) * 8 + d] = acc[rg][cg][r];
            }
        }
#undef LOADT
#undef WRITET
}

// ---------------- Attention partials: block = (kt, qc), 1 wave, 64 queries x 128 keys ----------------
// K/V rows are wave-uniform -> scalar(s_load) path; no LDS at all.
// Packed partial layout per head: segment kt at float offset 9*off(kt), off(kt)=64*kt*(17-kt);
// within segment: [d][Lkt] with Lkt = 1024-128*kt, index q-128*kt.
__global__ __launch_bounds__(64) void attn_part(
        const float* __restrict__ H, float* __restrict__ Part) {
    int rem = blockIdx.x;       // 0..71
    int kt = 0;
    while (rem >= 16 - 2 * kt) { rem -= 16 - 2 * kt; kt++; }
    const int qc = rem + 2 * kt;
    const int c = blockIdx.y, b = blockIdx.z;
    const int lane = threadIdx.x;

    const size_t hoff = (size_t)(b * 8 + c) * 8192;
    const float* Kg = H + 524288 + hoff + (size_t)kt * 1024;
    const float* Vg = H + 1048576 + hoff + (size_t)kt * 1024;

    const int q = qc * 64 + lane;
    const float* Qr = &H[hoff + (size_t)q * 8];
    const float sc = RS8 * LOG2E;    // fold softmax scale and log2(e) into q
    const float q0 = Qr[0] * sc, q1 = Qr[1] * sc, q2 = Qr[2] * sc, q3 = Qr[3] * sc;
    const float q4 = Qr[4] * sc, q5 = Qr[5] * sc, q6 = Qr[6] * sc, q7 = Qr[7] * sc;

    float l = 0.f;
    float a0 = 0.f, a1 = 0.f, a2 = 0.f, a3 = 0.f;
    float a4 = 0.f, a5 = 0.f, a6 = 0.f, a7 = 0.f;
    const int qmk = q - kt * 128;    // lane-varying causal bound

#define AITER(j, PRED) do { \
    const f32x4 ka = *(const f32x4*)&Kg[(j) * 8]; \
    const f32x4 kb = *(const f32x4*)&Kg[(j) * 8 + 4]; \
    float s = fmaf(q0, ka[0], fmaf(q1, ka[1], fmaf(q2, ka[2], fmaf(q3, ka[3], \
              fmaf(q4, kb[0], fmaf(q5, kb[1], fmaf(q6, kb[2], q7 * kb[3]))))))); \
    float p = exp2f(s); \
    if (PRED) p = ((j) <= qmk) ? p : 0.f; \
    l += p; \
    const f32x4 va = *(const f32x4*)&Vg[(j) * 8]; \
    const f32x4 vb = *(const f32x4*)&Vg[(j) * 8 + 4]; \
    a0 = fmaf(p, va[0], a0); a1 = fmaf(p, va[1], a1); \
    a2 = fmaf(p, va[2], a2); a3 = fmaf(p, va[3], a3); \
    a4 = fmaf(p, vb[0], a4); a5 = fmaf(p, vb[1], a5); \
    a6 = fmaf(p, vb[2], a6); a7 = fmaf(p, vb[3], a7); \
} while (0)

    if ((qc >> 1) == kt) {          // diagonal block: causal predicate
#pragma unroll 4
        for (int j = 0; j < 128; ++j) AITER(j, true);
    } else {                        // strictly below diagonal: all keys active
#pragma unroll 4
        for (int j = 0; j < 128; ++j) AITER(j, false);
    }
#undef AITER

    const int Lkt = 1024 - 128 * kt;
    float* ph = Part + (size_t)(b * 8 + c) * 41472 + (size_t)9 * 64 * kt * (17 - kt);
    const int idx = qmk;
    ph[0 * Lkt + idx] = l;
    ph[1 * Lkt + idx] = a0; ph[2 * Lkt + idx] = a1;
    ph[3 * Lkt + idx] = a2; ph[4 * Lkt + idx] = a3;
    ph[5 * Lkt + idx] = a4; ph[6 * Lkt + idx] = a5;
    ph[7 * Lkt + idx] = a6; ph[8 * Lkt + idx] = a7;
}

// ---------------- Combine partials: out = x + (qm/l) * acc ----------------
__global__ __launch_bounds__(64) void attn_comb(
        const float* __restrict__ Part, const float* __restrict__ x,
        const float* __restrict__ pm, float* __restrict__ out) {
    const int qc = blockIdx.x, c = blockIdx.y, b = blockIdx.z;
    const int lane = threadIdx.x;
    const int q = qc * 64 + lane;
    const int nkt = (qc >> 1) + 1;

    float t[9];
#pragma unroll
    for (int d = 0; d < 9; d++) t[d] = 0.f;

    const float* ph = Part + (size_t)(b * 8 + c) * 41472;
    for (int kt = 0; kt < nkt; kt++) {
        const int Lkt = 1024 - 128 * kt;
        const float* seg = ph + (size_t)9 * 64 * kt * (17 - kt);
        const int idx = q - 128 * kt;
#pragma unroll
        for (int d = 0; d < 9; d++) t[d] += seg[d * Lkt + idx];
    }

    const float qm = pm[b * L_SEQ + q];
    const float r = qm / t[0];             // qm==0 -> r=0 -> out = x exactly
    const float* xrow = &x[(size_t)b * LM + (size_t)q * NM + c * 8];
    float* orow = &out[(size_t)b * LM + (size_t)q * NM + c * 8];
    float4 x0 = *(const float4*)&xrow[0];
    float4 x1 = *(const float4*)&xrow[4];
    float4 o0 = make_float4(fmaf(t[1], r, x0.x), fmaf(t[2], r, x0.y),
                            fmaf(t[3], r, x0.z), fmaf(t[4], r, x0.w));
    float4 o1 = make_float4(fmaf(t[5], r, x1.x), fmaf(t[6], r, x1.y),
                            fmaf(t[7], r, x1.z), fmaf(t[8], r, x1.w));
    *(float4*)&orow[0] = o0;
    *(float4*)&orow[4] = o1;
}

// ---------------- Output 2: attention[b][k] = qm(b,1023)/8 * sum_c softmax_row_c[k] ----------------
__global__ __launch_bounds__(256) void out2_kernel(
        const float* __restrict__ H, const float* __restrict__ pm,
        float* __restrict__ out2) {
    const int b = blockIdx.x;
    const int tid = threadIdx.x;
    const int lane = tid & 63, wv = tid >> 6;
    __shared__ float red[4];
    const float qm = pm[b * L_SEQ + 1023];
    const float sc = RS8 * LOG2E;
    float acc[4] = {0.f, 0.f, 0.f, 0.f};
    for (int cc = 0; cc < 8; cc++) {
        const size_t hoff = (size_t)(b * 8 + cc) * 8192;
        const float* Qr = &H[hoff + (size_t)1023 * 8];
        const float q0 = Qr[0] * sc, q1 = Qr[1] * sc, q2 = Qr[2] * sc, q3 = Qr[3] * sc;
        const float q4 = Qr[4] * sc, q5 = Qr[5] * sc, q6 = Qr[6] * sc, q7 = Qr[7] * sc;
        const float* Kg = H + 524288 + hoff;
        float p[4];
        float ts = 0.f;
#pragma unroll
        for (int i = 0; i < 4; i++) {
            int k = tid + 256 * i;
            const f32x4 ka = *(const f32x4*)&Kg[(size_t)k * 8];
            const f32x4 kb = *(const f32x4*)&Kg[(size_t)k * 8 + 4];
            float d = fmaf(q0, ka[0], fmaf(q1, ka[1], fmaf(q2, ka[2], fmaf(q3, ka[3],
                      fmaf(q4, kb[0], fmaf(q5, kb[1], fmaf(q6, kb[2], q7 * kb[3])))))));
            p[i] = exp2f(d);
            ts += p[i];
        }
        ts = wredsum(ts);
        if (lane == 0) red[wv] = ts;
        __syncthreads();
        const float Ls = red[0] + red[1] + red[2] + red[3];
        __syncthreads();
        const float inv = 0.125f / Ls;
#pragma unroll
        for (int i = 0; i < 4; i++) acc[i] = fmaf(p[i], inv, acc[i]);
    }
#pragma unroll
    for (int i = 0; i < 4; i++) out2[b * L_SEQ + tid + 256 * i] = acc[i] * qm;
}

extern "C" void kernel_launch(void* const* d_in, const int* in_sizes, int n_in,
                              void* d_out, int out_size, void* d_ws, size_t ws_size,
                              hipStream_t stream) {
    const float* x  = (const float*)d_in[0];
    const float* pm = (const float*)d_in[1];
    const float* Wq = (const float*)d_in[2];
    const float* Wk = (const float*)d_in[3];
    const float* Wv = (const float*)d_in[4];

    float* H    = (float*)d_ws;                            // 6 MB fp32 head-major Q,K,V
    u16* Wbf    = (u16*)((char*)d_ws + 6291456);           // 6 MB bf16 W[3][1024][1024]
    u16* xT     = (u16*)((char*)d_ws + 12582912);          // 1 MB bf16 xT[8][64][1024]
    float* Part = (float*)((char*)d_ws + 13631488);        // 10.6 MB fp32 packed partials
    float* out  = (float*)d_out;                           // [8,1024,64] then [8,1024]

    hipLaunchKernelGGL(prep_kernel, dim3(1664), dim3(256), 0, stream, x, Wq, Wk, Wv, Wbf, xT);
    hipLaunchKernelGGL(proj_mfma, dim3(32, 8, 3), dim3(64), 0, stream, Wbf, xT, H);
    hipLaunchKernelGGL(attn_part, dim3(72, 8, 8), dim3(64), 0, stream, H, Part);
    hipLaunchKernelGGL(attn_comb, dim3(16, 8, 8), dim3(64), 0, stream, Part, x, pm, out);
    hipLaunchKernelGGL(out2_kernel, dim3(8), dim3(256), 0, stream, H, pm, out + BLM);
}

// Round 7
// 65.861 us; speedup vs baseline: 1.0257x; 1.0257x over previous
//
#include <hip/hip_runtime.h>

#define L_SEQ 1024
#define NB 8
#define NM 64
#define LM (L_SEQ * NM)    // 65536
#define BLM (NB * LM)      // 524288
#define RS8 0.35355339059327373f
#define LOG2E 1.4426950408889634f

typedef unsigned short u16;
typedef __attribute__((ext_vector_type(8))) short short8;
typedef __attribute__((ext_vector_type(4))) float f32x4;
typedef __attribute__((ext_vector_type(8))) u16 us8;

__device__ __forceinline__ float wredsum(float v) {
#pragma unroll
    for (int off = 32; off; off >>= 1) v += __shfl_xor(v, off);
    return v;
}

__device__ __forceinline__ u16 f2bf(float f) {
    unsigned int u = __float_as_uint(f);
    unsigned int r = (u + 0x7FFFu + ((u >> 16) & 1u)) >> 16;
    return (u16)r;
}

// ---------------- Prep: W fp32 -> bf16 (same layout); x[b][k][m] -> xT[b][m][k] bf16 ----------------
__global__ __launch_bounds__(256) void prep_kernel(
        const float* __restrict__ x, const float* __restrict__ Wq,
        const float* __restrict__ Wk, const float* __restrict__ Wv,
        u16* __restrict__ Wbf, u16* __restrict__ xT) {
    const int bx = blockIdx.x;
    const int tid = threadIdx.x;
    if (bx < 1536) {                       // W convert: 3 x 512 blocks x 2048 elements
        const int w = bx >> 9;
        const int blk = bx & 511;
        const float* W = (w == 0) ? Wq : (w == 1) ? Wk : Wv;
        const size_t base = (size_t)blk * 2048 + (size_t)tid * 8;
        float4 f0 = *(const float4*)&W[base];
        float4 f1 = *(const float4*)&W[base + 4];
        us8 o;
        o[0] = f2bf(f0.x); o[1] = f2bf(f0.y); o[2] = f2bf(f0.z); o[3] = f2bf(f0.w);
        o[4] = f2bf(f1.x); o[5] = f2bf(f1.y); o[6] = f2bf(f1.z); o[7] = f2bf(f1.w);
        *(us8*)&Wbf[(size_t)w * 1048576 + base] = o;
    } else {                               // x transpose: 128 blocks (b, ktile)
        const int blk = bx - 1536;
        const int b = blk >> 4, kt = blk & 15;
        __shared__ float T[64][65];
        const int r16 = tid >> 4, c4 = (tid & 15) * 4;
#pragma unroll
        for (int s = 0; s < 4; s++) {
            int r = r16 + s * 16;
            *(float4*)&T[r][c4] = *(const float4*)&x[((size_t)b * L_SEQ + kt * 64 + r) * NM + c4];
        }
        __syncthreads();
        const int m = tid >> 2;
#pragma unroll
        for (int s = 0; s < 2; s++) {
            int c = (tid & 3) * 2 + s;
            int k0 = c * 8;
            us8 o;
#pragma unroll
            for (int j = 0; j < 8; j++) o[j] = f2bf(T[k0 + j][m]);
            *(us8*)&xT[((size_t)b * NM + m) * L_SEQ + kt * 64 + k0] = o;
        }
    }
}

// ---------------- Projection via MFMA -> head-major fp32 H[w][b][c][seq][8] ----------------
__global__ __launch_bounds__(64) void proj_mfma(
        const u16* __restrict__ Wbf, const u16* __restrict__ xT,
        float* __restrict__ H) {
    const int it = blockIdx.x;   // 32 row tiles
    const int b  = blockIdx.y;   // 8
    const int w  = blockIdx.z;   // 3
    const int l  = threadIdx.x;

    __shared__ __align__(16) u16 Ab[2][2048];   // [32 rows][64 k] swizzled
    __shared__ __align__(16) u16 Bb[2][4096];   // [64 m][64 k] swizzled

    const u16* As = Wbf + (size_t)w * 1048576 + (size_t)(it * 32) * L_SEQ;
    const u16* Bs = xT + (size_t)b * (NM * L_SEQ);

    const int soff = (l >> 3) * L_SEQ + (((l & 7) ^ (l >> 3)) * 8);
    const int ldst = l * 8;

    f32x4 acc[2][4];
#pragma unroll
    for (int i = 0; i < 2; i++)
#pragma unroll
        for (int j = 0; j < 4; j++) acc[i][j] = (f32x4){0.f, 0.f, 0.f, 0.f};

    short8 ra[4], rb[8];

#define LOADT(kt)  do { \
    _Pragma("unroll") for (int t = 0; t < 4; t++) ra[t] = *(const short8*)&As[(size_t)t * 8192 + soff + (kt) * 64]; \
    _Pragma("unroll") for (int t = 0; t < 8; t++) rb[t] = *(const short8*)&Bs[(size_t)t * 8192 + soff + (kt) * 64]; \
} while (0)
#define WRITET(cur) do { \
    _Pragma("unroll") for (int t = 0; t < 4; t++) *(short8*)&Ab[cur][t * 512 + ldst] = ra[t]; \
    _Pragma("unroll") for (int t = 0; t < 8; t++) *(short8*)&Bb[cur][t * 512 + ldst] = rb[t]; \
} while (0)

    const int frow = l & 15;
    const int fg = l >> 4;
    const int lx = l & 7;

    LOADT(0);
    WRITET(0);
    LOADT(1);

    for (int kt = 0; kt < 16; ++kt) {
        const int cur = kt & 1;
        __syncthreads();
#pragma unroll
        for (int ks = 0; ks < 2; ++ks) {
            const int ch = ((ks * 4 + fg) ^ lx) * 8;
            short8 af0 = *(const short8*)&Ab[cur][frow * 64 + ch];
            short8 af1 = *(const short8*)&Ab[cur][(16 + frow) * 64 + ch];
#pragma unroll
            for (int cg = 0; cg < 4; ++cg) {
                short8 bf = *(const short8*)&Bb[cur][(cg * 16 + frow) * 64 + ch];
                acc[0][cg] = __builtin_amdgcn_mfma_f32_16x16x32_bf16(af0, bf, acc[0][cg], 0, 0, 0);
                acc[1][cg] = __builtin_amdgcn_mfma_f32_16x16x32_bf16(af1, bf, acc[1][cg], 0, 0, 0);
            }
        }
        if (kt < 15) {
            WRITET(cur ^ 1);
            if (kt < 14) LOADT(kt + 2);
        }
    }

    // head-major fp32 store: H[w][b][c][i][d], c = m>>3, d = m&7
    float* dst = H + (size_t)w * 524288 + (size_t)b * 65536;
#pragma unroll
    for (int rg = 0; rg < 2; ++rg)
#pragma unroll
        for (int cg = 0; cg < 4; ++cg) {
            const int m = cg * 16 + frow;
            const int cc = m >> 3, d = m & 7;
#pragma unroll
            for (int r = 0; r < 4; ++r) {
                const int iq = it * 32 + rg * 16 + fg * 4 + r;
                dst[((size_t)cc * L_SEQ + iq) * 8 + d] = acc[rg][cg][r];
            }
        }
#undef LOADT
#undef WRITET
}

// ---------------- Attention partials: block = (qt 256 queries, kt 128 keys), 4 waves ----------------
// 20 causal (qt,kt) pairs per head. Wave wv handles queries qt*256+wv*64..+63 over the shared
// 128-key LDS tile. Partials additive (no-max softmax) -> packed Part segments, combined later.
// Segment kt at float offset 9*64*kt*(17-kt); within: [d][Lkt], Lkt=1024-128*kt, idx=q-128*kt.
__global__ __launch_bounds__(256) void attn_part(
        const float* __restrict__ H, float* __restrict__ Part) {
    const int bid = blockIdx.x;     // 0..19
    int qt, kt;
    if (bid < 2)       { qt = 0; kt = bid; }
    else if (bid < 6)  { qt = 1; kt = bid - 2; }
    else if (bid < 12) { qt = 2; kt = bid - 6; }
    else               { qt = 3; kt = bid - 12; }
    const int c = blockIdx.y, b = blockIdx.z;
    const int tid = threadIdx.x, wv = tid >> 6, lane = tid & 63;

    __shared__ __align__(16) float KV[2048];   // K[128][8] @0, V[128][8] @1024

    const size_t hoff = (size_t)(b * 8 + c) * 8192;
    const float* Kg = H + 524288 + hoff + (size_t)kt * 1024;
    const float* Vg = H + 1048576 + hoff + (size_t)kt * 1024;
    {
        const int i = tid * 4;
        *(f32x4*)&KV[i]        = *(const f32x4*)&Kg[i];
        *(f32x4*)&KV[1024 + i] = *(const f32x4*)&Vg[i];
    }

    const int q = qt * 256 + wv * 64 + lane;
    const int qmk = q - kt * 128;              // causal bound within tile
    const float* Qr = &H[hoff + (size_t)q * 8];
    const float sc = RS8 * LOG2E;
    const float q0 = Qr[0] * sc, q1 = Qr[1] * sc, q2 = Qr[2] * sc, q3 = Qr[3] * sc;
    const float q4 = Qr[4] * sc, q5 = Qr[5] * sc, q6 = Qr[6] * sc, q7 = Qr[7] * sc;

    __syncthreads();

    // wave-uniform activity: active iff wave's min q >= kt*128 (boundaries are 64-aligned)
    if (qmk - lane < 0) return;

    float l = 0.f;
    float a0 = 0.f, a1 = 0.f, a2 = 0.f, a3 = 0.f;
    float a4 = 0.f, a5 = 0.f, a6 = 0.f, a7 = 0.f;

#define AITER(j, PRED) do { \
    const f32x4 ka = *(const f32x4*)&KV[(j) * 8]; \
    const f32x4 kb = *(const f32x4*)&KV[(j) * 8 + 4]; \
    float sa = fmaf(q0, ka[0], fmaf(q1, ka[1], fmaf(q2, ka[2], q3 * ka[3]))); \
    float sb = fmaf(q4, kb[0], fmaf(q5, kb[1], fmaf(q6, kb[2], q7 * kb[3]))); \
    float p = exp2f(sa + sb); \
    if (PRED) p = ((j) <= qmk) ? p : 0.f; \
    l += p; \
    const f32x4 va = *(const f32x4*)&KV[1024 + (j) * 8]; \
    const f32x4 vb = *(const f32x4*)&KV[1024 + (j) * 8 + 4]; \
    a0 = fmaf(p, va[0], a0); a1 = fmaf(p, va[1], a1); \
    a2 = fmaf(p, va[2], a2); a3 = fmaf(p, va[3], a3); \
    a4 = fmaf(p, vb[0], a4); a5 = fmaf(p, vb[1], a5); \
    a6 = fmaf(p, vb[2], a6); a7 = fmaf(p, vb[3], a7); \
} while (0)

    if (qmk - lane >= 128) {        // strictly below the diagonal tile: all 128 keys active
#pragma unroll 8
        for (int j = 0; j < 128; ++j) AITER(j, false);
    } else {                        // diagonal tile: per-lane causal predicate
#pragma unroll 8
        for (int j = 0; j < 128; ++j) AITER(j, true);
    }
#undef AITER

    const int Lkt = 1024 - 128 * kt;
    float* ph = Part + (size_t)(b * 8 + c) * 41472 + (size_t)9 * 64 * kt * (17 - kt);
    ph[0 * Lkt + qmk] = l;
    ph[1 * Lkt + qmk] = a0; ph[2 * Lkt + qmk] = a1;
    ph[3 * Lkt + qmk] = a2; ph[4 * Lkt + qmk] = a3;
    ph[5 * Lkt + qmk] = a4; ph[6 * Lkt + qmk] = a5;
    ph[7 * Lkt + qmk] = a6; ph[8 * Lkt + qmk] = a7;
}

// ---------------- Combine partials: out = x + (qm/l) * acc ----------------
__global__ __launch_bounds__(64) void attn_comb(
        const float* __restrict__ Part, const float* __restrict__ x,
        const float* __restrict__ pm, float* __restrict__ out) {
    const int qc = blockIdx.x, c = blockIdx.y, b = blockIdx.z;
    const int lane = threadIdx.x;
    const int q = qc * 64 + lane;
    const int nkt = (qc >> 1) + 1;

    float t[9];
#pragma unroll
    for (int d = 0; d < 9; d++) t[d] = 0.f;

    const float* ph = Part + (size_t)(b * 8 + c) * 41472;
    for (int kt = 0; kt < nkt; kt++) {
        const int Lkt = 1024 - 128 * kt;
        const float* seg = ph + (size_t)9 * 64 * kt * (17 - kt);
        const int idx = q - 128 * kt;
#pragma unroll
        for (int d = 0; d < 9; d++) t[d] += seg[d * Lkt + idx];
    }

    const float qm = pm[b * L_SEQ + q];
    const float r = qm / t[0];             // qm==0 -> r=0 -> out = x exactly
    const float* xrow = &x[(size_t)b * LM + (size_t)q * NM + c * 8];
    float* orow = &out[(size_t)b * LM + (size_t)q * NM + c * 8];
    float4 x0 = *(const float4*)&xrow[0];
    float4 x1 = *(const float4*)&xrow[4];
    float4 o0 = make_float4(fmaf(t[1], r, x0.x), fmaf(t[2], r, x0.y),
                            fmaf(t[3], r, x0.z), fmaf(t[4], r, x0.w));
    float4 o1 = make_float4(fmaf(t[5], r, x1.x), fmaf(t[6], r, x1.y),
                            fmaf(t[7], r, x1.z), fmaf(t[8], r, x1.w));
    *(float4*)&orow[0] = o0;
    *(float4*)&orow[4] = o1;
}

// ---------------- Output 2, stage 1: per-head last-row softmax -> O2p[(b*8+c)][k] ----------------
__global__ __launch_bounds__(256) void out2_part(
        const float* __restrict__ H, float* __restrict__ O2p) {
    const int c = blockIdx.x, b = blockIdx.y;
    const int tid = threadIdx.x;
    const int lane = tid & 63, wv = tid >> 6;
    __shared__ float red[4];
    const size_t hoff = (size_t)(b * 8 + c) * 8192;
    const float sc = RS8 * LOG2E;
    const float* Qr = &H[hoff + (size_t)1023 * 8];
    const float q0 = Qr[0] * sc, q1 = Qr[1] * sc, q2 = Qr[2] * sc, q3 = Qr[3] * sc;
    const float q4 = Qr[4] * sc, q5 = Qr[5] * sc, q6 = Qr[6] * sc, q7 = Qr[7] * sc;
    const float* Kg = H + 524288 + hoff;
    float p[4];
    float ts = 0.f;
#pragma unroll
    for (int i = 0; i < 4; i++) {
        int k = tid + 256 * i;
        const f32x4 ka = *(const f32x4*)&Kg[(size_t)k * 8];
        const f32x4 kb = *(const f32x4*)&Kg[(size_t)k * 8 + 4];
        float sa = fmaf(q0, ka[0], fmaf(q1, ka[1], fmaf(q2, ka[2], q3 * ka[3])));
        float sb = fmaf(q4, kb[0], fmaf(q5, kb[1], fmaf(q6, kb[2], q7 * kb[3])));
        p[i] = exp2f(sa + sb);
        ts += p[i];
    }
    ts = wredsum(ts);
    if (lane == 0) red[wv] = ts;
    __syncthreads();
    const float inv = 0.125f / (red[0] + red[1] + red[2] + red[3]);
    float* dst = O2p + (size_t)(b * 8 + c) * L_SEQ;
#pragma unroll
    for (int i = 0; i < 4; i++) dst[tid + 256 * i] = p[i] * inv;
}

// ---------------- Output 2, stage 2: sum over c, scale by qm ----------------
__global__ __launch_bounds__(256) void out2_comb(
        const float* __restrict__ O2p, const float* __restrict__ pm,
        float* __restrict__ out2) {
    const int b = blockIdx.x;
    const int tid = threadIdx.x;
    const float qm = pm[b * L_SEQ + 1023];
    const float* src = O2p + (size_t)b * 8 * L_SEQ;
#pragma unroll
    for (int i = 0; i < 4; i++) {
        const int k = tid + 256 * i;
        float s = 0.f;
#pragma unroll
        for (int cc = 0; cc < 8; cc++) s += src[cc * L_SEQ + k];
        out2[b * L_SEQ + k] = s * qm;
    }
}

extern "C" void kernel_launch(void* const* d_in, const int* in_sizes, int n_in,
                              void* d_out, int out_size, void* d_ws, size_t ws_size,
                              hipStream_t stream) {
    const float* x  = (const float*)d_in[0];
    const float* pm = (const float*)d_in[1];
    const float* Wq = (const float*)d_in[2];
    const float* Wk = (const float*)d_in[3];
    const float* Wv = (const float*)d_in[4];

    float* H    = (float*)d_ws;                            // 6 MB fp32 head-major Q,K,V
    u16* Wbf    = (u16*)((char*)d_ws + 6291456);           // 6 MB bf16 W[3][1024][1024]
    u16* xT     = (u16*)((char*)d_ws + 12582912);          // 1 MB bf16 xT[8][64][1024]
    float* Part = (float*)((char*)d_ws + 13631488);        // 10.6 MB fp32 packed partials
    float* O2p  = (float*)((char*)d_ws + 24248320);        // 256 KB fp32 out2 partials
    float* out  = (float*)d_out;                           // [8,1024,64] then [8,1024]

    hipLaunchKernelGGL(prep_kernel, dim3(1664), dim3(256), 0, stream, x, Wq, Wk, Wv, Wbf, xT);
    hipLaunchKernelGGL(proj_mfma, dim3(32, 8, 3), dim3(64), 0, stream, Wbf, xT, H);
    hipLaunchKernelGGL(attn_part, dim3(20, 8, 8), dim3(256), 0, stream, H, Part);
    hipLaunchKernelGGL(attn_comb, dim3(16, 8, 8), dim3(64), 0, stream, Part, x, pm, out);
    hipLaunchKernelGGL(out2_part, dim3(8, 8), dim3(256), 0, stream, H, O2p);
    hipLaunchKernelGGL(out2_comb, dim3(8), dim3(256), 0, stream, O2p, pm, out + BLM);
}

// Round 9
// 61.450 us; speedup vs baseline: 1.0994x; 1.0718x over previous
//
#include <hip/hip_runtime.h>

#define L_SEQ 1024
#define NB 8
#define NM 64
#define LM (L_SEQ * NM)    // 65536
#define BLM (NB * LM)      // 524288
#define RS8 0.35355339059327373f
#define LOG2E 1.4426950408889634f

typedef unsigned short u16;
typedef unsigned int u32;
typedef __attribute__((ext_vector_type(8))) short short8;
typedef __attribute__((ext_vector_type(4))) float f32x4;
typedef __attribute__((ext_vector_type(8))) u16 us8;

__device__ __forceinline__ float wredsum(float v) {
#pragma unroll
    for (int off = 32; off; off >>= 1) v += __shfl_xor(v, off);
    return v;
}

__device__ __forceinline__ u16 f2bf(float f) {
    u32 u = __float_as_uint(f);
    u32 r = (u + 0x7FFFu + ((u >> 16) & 1u)) >> 16;
    return (u16)r;
}
__device__ __forceinline__ float bf2f(u16 u) {
    return __uint_as_float((u32)u << 16);
}
__device__ __forceinline__ u32 pack2bf(float lo, float hi) {
    return ((u32)f2bf(hi) << 16) | (u32)f2bf(lo);
}

// ---------------- Prep: W fp32 -> bf16 (same layout); x[b][k][m] -> xT[b][m][k] bf16 ----------------
__global__ __launch_bounds__(256) void prep_kernel(
        const float* __restrict__ x, const float* __restrict__ Wq,
        const float* __restrict__ Wk, const float* __restrict__ Wv,
        u16* __restrict__ Wbf, u16* __restrict__ xT) {
    const int bx = blockIdx.x;
    const int tid = threadIdx.x;
    if (bx < 1536) {                       // W convert: 3 x 512 blocks x 2048 elements
        const int w = bx >> 9;
        const int blk = bx & 511;
        const float* W = (w == 0) ? Wq : (w == 1) ? Wk : Wv;
        const size_t base = (size_t)blk * 2048 + (size_t)tid * 8;
        float4 f0 = *(const float4*)&W[base];
        float4 f1 = *(const float4*)&W[base + 4];
        us8 o;
        o[0] = f2bf(f0.x); o[1] = f2bf(f0.y); o[2] = f2bf(f0.z); o[3] = f2bf(f0.w);
        o[4] = f2bf(f1.x); o[5] = f2bf(f1.y); o[6] = f2bf(f1.z); o[7] = f2bf(f1.w);
        *(us8*)&Wbf[(size_t)w * 1048576 + base] = o;
    } else {                               // x transpose: 128 blocks (b, ktile)
        const int blk = bx - 1536;
        const int b = blk >> 4, kt = blk & 15;
        __shared__ float T[64][65];
        const int r16 = tid >> 4, c4 = (tid & 15) * 4;
#pragma unroll
        for (int s = 0; s < 4; s++) {
            int r = r16 + s * 16;
            *(float4*)&T[r][c4] = *(const float4*)&x[((size_t)b * L_SEQ + kt * 64 + r) * NM + c4];
        }
        __syncthreads();
        const int m = tid >> 2;
#pragma unroll
        for (int s = 0; s < 2; s++) {
            int c = (tid & 3) * 2 + s;
            int k0 = c * 8;
            us8 o;
#pragma unroll
            for (int j = 0; j < 8; j++) o[j] = f2bf(T[k0 + j][m]);
            *(us8*)&xT[((size_t)b * NM + m) * L_SEQ + kt * 64 + k0] = o;
        }
    }
}

// ---------------- Projection via MFMA -> head-major bf16 H[w][b][c][seq][8]; V also transposed ----------------
__global__ __launch_bounds__(64) void proj_mfma(
        const u16* __restrict__ Wbf, const u16* __restrict__ xT,
        u16* __restrict__ H, u16* __restrict__ VtG) {
    const int it = blockIdx.x;   // 32 row tiles
    const int b  = blockIdx.y;   // 8
    const int w  = blockIdx.z;   // 3
    const int l  = threadIdx.x;

    __shared__ __align__(16) u16 Ab[2][2048];   // [32 rows][64 k] swizzled
    __shared__ __align__(16) u16 Bb[2][4096];   // [64 m][64 k] swizzled

    const u16* As = Wbf + (size_t)w * 1048576 + (size_t)(it * 32) * L_SEQ;
    const u16* Bs = xT + (size_t)b * (NM * L_SEQ);

    const int soff = (l >> 3) * L_SEQ + (((l & 7) ^ (l >> 3)) * 8);
    const int ldst = l * 8;

    f32x4 acc[2][4];
#pragma unroll
    for (int i = 0; i < 2; i++)
#pragma unroll
        for (int j = 0; j < 4; j++) acc[i][j] = (f32x4){0.f, 0.f, 0.f, 0.f};

    short8 ra[4], rb[8];

#define LOADT(kt)  do { \
    _Pragma("unroll") for (int t = 0; t < 4; t++) ra[t] = *(const short8*)&As[(size_t)t * 8192 + soff + (kt) * 64]; \
    _Pragma("unroll") for (int t = 0; t < 8; t++) rb[t] = *(const short8*)&Bs[(size_t)t * 8192 + soff + (kt) * 64]; \
} while (0)
#define WRITET(cur) do { \
    _Pragma("unroll") for (int t = 0; t < 4; t++) *(short8*)&Ab[cur][t * 512 + ldst] = ra[t]; \
    _Pragma("unroll") for (int t = 0; t < 8; t++) *(short8*)&Bb[cur][t * 512 + ldst] = rb[t]; \
} while (0)

    const int frow = l & 15;
    const int fg = l >> 4;
    const int lx = l & 7;

    LOADT(0);
    WRITET(0);
    LOADT(1);

    for (int kt = 0; kt < 16; ++kt) {
        const int cur = kt & 1;
        __syncthreads();
#pragma unroll
        for (int ks = 0; ks < 2; ++ks) {
            const int ch = ((ks * 4 + fg) ^ lx) * 8;
            short8 af0 = *(const short8*)&Ab[cur][frow * 64 + ch];
            short8 af1 = *(const short8*)&Ab[cur][(16 + frow) * 64 + ch];
#pragma unroll
            for (int cg = 0; cg < 4; ++cg) {
                short8 bf = *(const short8*)&Bb[cur][(cg * 16 + frow) * 64 + ch];
                acc[0][cg] = __builtin_amdgcn_mfma_f32_16x16x32_bf16(af0, bf, acc[0][cg], 0, 0, 0);
                acc[1][cg] = __builtin_amdgcn_mfma_f32_16x16x32_bf16(af1, bf, acc[1][cg], 0, 0, 0);
            }
        }
        if (kt < 15) {
            WRITET(cur ^ 1);
            if (kt < 14) LOADT(kt + 2);
        }
    }

    // head-major bf16 store: H[w][b][c][i][d], c = m>>3, d = m&7; V additionally transposed
    u16* dst = H + (size_t)w * 524288 + (size_t)b * 65536;
#pragma unroll
    for (int rg = 0; rg < 2; ++rg)
#pragma unroll
        for (int cg = 0; cg < 4; ++cg) {
            const int m = cg * 16 + frow;
            const int cc = m >> 3, d = m & 7;
#pragma unroll
            for (int r = 0; r < 4; ++r) {
                const int iq = it * 32 + rg * 16 + fg * 4 + r;
                const u16 val = f2bf(acc[rg][cg][r]);
                dst[((size_t)cc * L_SEQ + iq) * 8 + d] = val;
                if (w == 2)
                    VtG[((size_t)(b * 8 + cc) * 8 + d) * L_SEQ + iq] = val;
            }
        }
#undef LOADT
#undef WRITET
}

// ---------------- MFMA attention: block = (head, 64-query tile), 4 waves x 16-query strips ----------------
// S^T = mfma(A=K16, B=Q) with depth 8 zero-padded to 32; lane holds S^T[4g+r, q=l&15].
// P rebuilt to B-frag P^T[32k x 16q]: dest (qtil,g) needs keys 8g..8g+7 = half (g>>1 ? B : A)
// of source lanes g' = 2(g&1)+{0,1}. Shuffle BOTH halves, select by dest g (round-8 bug fix).
__global__ __launch_bounds__(256) void attn_mfma(
        const u16* __restrict__ H, const u16* __restrict__ VtG,
        const float* __restrict__ x, const float* __restrict__ pm,
        float* __restrict__ out) {
    const int qb = blockIdx.x;   // 16 query tiles of 64
    const int c  = blockIdx.y;   // 8
    const int b  = blockIdx.z;   // 8
    const int tid = threadIdx.x;
    const int wv = tid >> 6, lane = tid & 63;
    const int qtil = lane & 15, g = lane >> 4;

    __shared__ __align__(16) u16 Kl[8192];          // [1024 keys][8 d] bf16
    __shared__ __align__(16) u16 Vtl[8 * 1032];     // [8 d][1024+8 keys] bf16 (padded rows)

    const size_t hoff = (size_t)(b * 8 + c) * 8192;
    const u16* HQ = H + hoff;
    const u16* HK = H + 524288 + hoff;
    const int kend = (qb + 1) * 64;

    // stage K rows (bf16 copy)
    for (int k = tid; k < kend; k += 256)
        *(us8*)&Kl[k * 8] = *(const us8*)&HK[(size_t)k * 8];
    // stage V^T rows
    {
        const int vd = tid >> 5;                    // 0..7
        const u16* src = VtG + ((size_t)(b * 8 + c) * 8 + vd) * L_SEQ;
        for (int k8 = (tid & 31) * 8; k8 < kend; k8 += 256)
            *(us8*)&Vtl[vd * 1032 + k8] = *(const us8*)&src[k8];
    }

    // Q fragment (scaled, bf16), lanes g=0 carry d0..7, others zero-pad depth
    const int q = qb * 64 + wv * 16 + qtil;
    short8 qf = {0, 0, 0, 0, 0, 0, 0, 0};
    {
        us8 qv = *(const us8*)&HQ[(size_t)q * 8];
        if (g == 0) {
            const float sc = RS8 * LOG2E;
#pragma unroll
            for (int j = 0; j < 8; j++) qf[j] = (short)f2bf(bf2f(qv[j]) * sc);
        }
    }

    __syncthreads();

    const f32x4 czero = {0.f, 0.f, 0.f, 0.f};
    f32x4 oacc = czero;
    float lsum = 0.f;
    const short8 z8 = {0, 0, 0, 0, 0, 0, 0, 0};

    // chunks of 32 keys; this wave needs keys < qb*64 + (wv+1)*16
    const int nch = (qb * 64 + wv * 16 + 47) >> 5;
    for (int ch = 0; ch < nch; ++ch) {
        const int kb = ch * 32;
        short8 kfA = z8, kfB = z8;
        if (g == 0) {
            kfA = *(const short8*)&Kl[(kb + qtil) * 8];
            kfB = *(const short8*)&Kl[(kb + 16 + qtil) * 8];
        }
        f32x4 dA = __builtin_amdgcn_mfma_f32_16x16x32_bf16(kfA, qf, czero, 0, 0, 0);
        f32x4 dB = __builtin_amdgcn_mfma_f32_16x16x32_bf16(kfB, qf, czero, 0, 0, 0);

        float pA[4], pB[4];
        const int keyA = kb + 4 * g;
#pragma unroll
        for (int r = 0; r < 4; r++) {
            pA[r] = (keyA + r <= q) ? exp2f(dA[r]) : 0.f;
            pB[r] = (keyA + 16 + r <= q) ? exp2f(dB[r]) : 0.f;
            lsum += pA[r] + pB[r];
        }
        const u32 A01 = pack2bf(pA[0], pA[1]), A23 = pack2bf(pA[2], pA[3]);
        const u32 B01 = pack2bf(pB[0], pB[1]), B23 = pack2bf(pB[2], pB[3]);
        // dest (qtil,g): sources g' = 2(g&1)+{0,1}; half chosen by DEST g>>1 (post-shuffle select)
        const int src = qtil + ((g & 1) << 5);
        const u32 a0 = (u32)__shfl((int)A01, src, 64);
        const u32 a1 = (u32)__shfl((int)A23, src, 64);
        const u32 a2 = (u32)__shfl((int)A01, src + 16, 64);
        const u32 a3 = (u32)__shfl((int)A23, src + 16, 64);
        const u32 b0 = (u32)__shfl((int)B01, src, 64);
        const u32 b1 = (u32)__shfl((int)B23, src, 64);
        const u32 b2 = (u32)__shfl((int)B01, src + 16, 64);
        const u32 b3 = (u32)__shfl((int)B23, src + 16, 64);
        union { u32 u[4]; short8 s; } pu;
        pu.u[0] = (g < 2) ? a0 : b0;
        pu.u[1] = (g < 2) ? a1 : b1;
        pu.u[2] = (g < 2) ? a2 : b2;
        pu.u[3] = (g < 2) ? a3 : b3;

        short8 vf = z8;
        if (qtil < 8) vf = *(const short8*)&Vtl[qtil * 1032 + kb + 8 * g];
        oacc = __builtin_amdgcn_mfma_f32_16x16x32_bf16(vf, pu.s, oacc, 0, 0, 0);
    }

    // total l per query (4 lanes share a query column)
    lsum += __shfl_xor(lsum, 16);
    lsum += __shfl_xor(lsum, 32);

    if (g < 2) {       // lane holds O[q][4g..4g+3]
        const float qm = pm[b * L_SEQ + q];
        const float r8 = qm / lsum;          // qm==0 -> out = x exactly
        const size_t off = (size_t)b * LM + (size_t)q * NM + c * 8 + g * 4;
        float4 xv = *(const float4*)&x[off];
        float4 o = make_float4(fmaf(oacc[0], r8, xv.x), fmaf(oacc[1], r8, xv.y),
                               fmaf(oacc[2], r8, xv.z), fmaf(oacc[3], r8, xv.w));
        *(float4*)&out[off] = o;
    }
}

// ---------------- Output 2, stage 1: per-head last-row softmax -> O2p[(b*8+c)][k] ----------------
__global__ __launch_bounds__(256) void out2_part(
        const u16* __restrict__ H, float* __restrict__ O2p) {
    const int c = blockIdx.x, b = blockIdx.y;
    const int tid = threadIdx.x;
    const int lane = tid & 63, wv = tid >> 6;
    __shared__ float red[4];
    const size_t hoff = (size_t)(b * 8 + c) * 8192;
    const float sc = RS8 * LOG2E;
    us8 qv = *(const us8*)&H[hoff + (size_t)1023 * 8];
    const float q0 = bf2f(qv[0]) * sc, q1 = bf2f(qv[1]) * sc;
    const float q2 = bf2f(qv[2]) * sc, q3 = bf2f(qv[3]) * sc;
    const float q4 = bf2f(qv[4]) * sc, q5 = bf2f(qv[5]) * sc;
    const float q6 = bf2f(qv[6]) * sc, q7 = bf2f(qv[7]) * sc;
    const u16* Kg = H + 524288 + hoff;
    float p[4];
    float ts = 0.f;
#pragma unroll
    for (int i = 0; i < 4; i++) {
        int k = tid + 256 * i;
        us8 kv = *(const us8*)&Kg[(size_t)k * 8];
        float sa = fmaf(q0, bf2f(kv[0]), fmaf(q1, bf2f(kv[1]), fmaf(q2, bf2f(kv[2]), q3 * bf2f(kv[3]))));
        float sb = fmaf(q4, bf2f(kv[4]), fmaf(q5, bf2f(kv[5]), fmaf(q6, bf2f(kv[6]), q7 * bf2f(kv[7]))));
        p[i] = exp2f(sa + sb);
        ts += p[i];
    }
    ts = wredsum(ts);
    if (lane == 0) red[wv] = ts;
    __syncthreads();
    const float inv = 0.125f / (red[0] + red[1] + red[2] + red[3]);
    float* dst = O2p + (size_t)(b * 8 + c) * L_SEQ;
#pragma unroll
    for (int i = 0; i < 4; i++) dst[tid + 256 * i] = p[i] * inv;
}

// ---------------- Output 2, stage 2: sum over c, scale by qm ----------------
__global__ __launch_bounds__(256) void out2_comb(
        const float* __restrict__ O2p, const float* __restrict__ pm,
        float* __restrict__ out2) {
    const int b = blockIdx.x;
    const int tid = threadIdx.x;
    const float qm = pm[b * L_SEQ + 1023];
    const float* src = O2p + (size_t)b * 8 * L_SEQ;
#pragma unroll
    for (int i = 0; i < 4; i++) {
        const int k = tid + 256 * i;
        float s = 0.f;
#pragma unroll
        for (int cc = 0; cc < 8; cc++) s += src[cc * L_SEQ + k];
        out2[b * L_SEQ + k] = s * qm;
    }
}

extern "C" void kernel_launch(void* const* d_in, const int* in_sizes, int n_in,
                              void* d_out, int out_size, void* d_ws, size_t ws_size,
                              hipStream_t stream) {
    const float* x  = (const float*)d_in[0];
    const float* pm = (const float*)d_in[1];
    const float* Wq = (const float*)d_in[2];
    const float* Wk = (const float*)d_in[3];
    const float* Wv = (const float*)d_in[4];

    u16* H    = (u16*)d_ws;                              // 3 MB bf16 head-major Q,K,V
    u16* Wbf  = (u16*)((char*)d_ws + 3145728);           // 6 MB bf16 W[3][1024][1024]
    u16* xT   = (u16*)((char*)d_ws + 9437184);           // 1 MB bf16 xT[8][64][1024]
    u16* VtG  = (u16*)((char*)d_ws + 10485760);          // 1 MB bf16 Vt[64 heads][8][1024]
    float* O2p = (float*)((char*)d_ws + 11534336);       // 256 KB fp32 out2 partials
    float* out = (float*)d_out;                          // [8,1024,64] then [8,1024]

    hipLaunchKernelGGL(prep_kernel, dim3(1664), dim3(256), 0, stream, x, Wq, Wk, Wv, Wbf, xT);
    hipLaunchKernelGGL(proj_mfma, dim3(32, 8, 3), dim3(64), 0, stream, Wbf, xT, H, VtG);
    hipLaunchKernelGGL(attn_mfma, dim3(16, 8, 8), dim3(256), 0, stream, H, VtG, x, pm, out);
    hipLaunchKernelGGL(out2_part, dim3(8, 8), dim3(256), 0, stream, H, O2p);
    hipLaunchKernelGGL(out2_comb, dim3(8), dim3(256), 0, stream, O2p, pm, out + BLM);
}

// Round 11
// 58.020 us; speedup vs baseline: 1.1643x; 1.0591x over previous
//
#include <hip/hip_runtime.h>

#define L_SEQ 1024
#define NB 8
#define NM 64
#define LM (L_SEQ * NM)    // 65536
#define BLM (NB * LM)      // 524288
#define RS8 0.35355339059327373f
#define LOG2E 1.4426950408889634f

typedef unsigned short u16;
typedef unsigned int u32;
typedef __attribute__((ext_vector_type(8))) short short8;
typedef __attribute__((ext_vector_type(4))) float f32x4;
typedef __attribute__((ext_vector_type(8))) u16 us8;

__device__ __forceinline__ float wredsum(float v) {
#pragma unroll
    for (int off = 32; off; off >>= 1) v += __shfl_xor(v, off);
    return v;
}

__device__ __forceinline__ u16 f2bf(float f) {
    u32 u = __float_as_uint(f);
    u32 r = (u + 0x7FFFu + ((u >> 16) & 1u)) >> 16;
    return (u16)r;
}
__device__ __forceinline__ float bf2f(u16 u) {
    return __uint_as_float((u32)u << 16);
}
// packed RNE f32->bf16 pair: low half = lo, high half = hi (1 VALU op)
__device__ __forceinline__ u32 cvtpk(float lo, float hi) {
    u32 r;
    asm("v_cvt_pk_bf16_f32 %0, %1, %2" : "=v"(r) : "v"(lo), "v"(hi));
    return r;
}

// ---------------- Prep: W fp32 -> bf16 (same layout); x[b][k][m] -> xT[b][m][k] bf16 ----------------
__global__ __launch_bounds__(256) void prep_kernel(
        const float* __restrict__ x, const float* __restrict__ Wq,
        const float* __restrict__ Wk, const float* __restrict__ Wv,
        u16* __restrict__ Wbf, u16* __restrict__ xT) {
    const int bx = blockIdx.x;
    const int tid = threadIdx.x;
    if (bx < 1536) {                       // W convert: 3 x 512 blocks x 2048 elements
        const int w = bx >> 9;
        const int blk = bx & 511;
        const float* W = (w == 0) ? Wq : (w == 1) ? Wk : Wv;
        const size_t base = (size_t)blk * 2048 + (size_t)tid * 8;
        float4 f0 = *(const float4*)&W[base];
        float4 f1 = *(const float4*)&W[base + 4];
        us8 o;
        o[0] = f2bf(f0.x); o[1] = f2bf(f0.y); o[2] = f2bf(f0.z); o[3] = f2bf(f0.w);
        o[4] = f2bf(f1.x); o[5] = f2bf(f1.y); o[6] = f2bf(f1.z); o[7] = f2bf(f1.w);
        *(us8*)&Wbf[(size_t)w * 1048576 + base] = o;
    } else {                               // x transpose: 128 blocks (b, ktile)
        const int blk = bx - 1536;
        const int b = blk >> 4, kt = blk & 15;
        __shared__ float T[64][65];
        const int r16 = tid >> 4, c4 = (tid & 15) * 4;
#pragma unroll
        for (int s = 0; s < 4; s++) {
            int r = r16 + s * 16;
            *(float4*)&T[r][c4] = *(const float4*)&x[((size_t)b * L_SEQ + kt * 64 + r) * NM + c4];
        }
        __syncthreads();
        const int m = tid >> 2;
#pragma unroll
        for (int s = 0; s < 2; s++) {
            int c = (tid & 3) * 2 + s;
            int k0 = c * 8;
            us8 o;
#pragma unroll
            for (int j = 0; j < 8; j++) o[j] = f2bf(T[k0 + j][m]);
            *(us8*)&xT[((size_t)b * NM + m) * L_SEQ + kt * 64 + k0] = o;
        }
    }
}

// ---------------- Projection via MFMA -> head-major bf16 H[w][b][c][seq][8]; V also transposed ----------------
// BK=128 (two swizzled 64-k halves per barrier): 8 barriers instead of 16.
// NOTE: macro inner unroll var is `ti`; outer K-loop var is `tt` (round-10 bug: shadowed `t`).
__global__ __launch_bounds__(64) void proj_mfma(
        const u16* __restrict__ Wbf, const u16* __restrict__ xT,
        u16* __restrict__ H, u16* __restrict__ VtG) {
    const int b  = blockIdx.x;   // 8 (fastest: consecutive blocks share the W tile in L2)
    const int it = blockIdx.y;   // 32 row tiles
    const int w  = blockIdx.z;   // 3
    const int l  = threadIdx.x;

    __shared__ __align__(16) u16 Ab[2][2][2048];   // [dbuf][half][32 rows x 64 k] swizzled
    __shared__ __align__(16) u16 Bb[2][2][4096];   // [dbuf][half][64 m x 64 k] swizzled

    const u16* As = Wbf + (size_t)w * 1048576 + (size_t)(it * 32) * L_SEQ;
    const u16* Bs = xT + (size_t)b * (NM * L_SEQ);

    const int soff = (l >> 3) * L_SEQ + (((l & 7) ^ (l >> 3)) * 8);
    const int ldst = l * 8;

    f32x4 acc[2][4];
#pragma unroll
    for (int i = 0; i < 2; i++)
#pragma unroll
        for (int j = 0; j < 4; j++) acc[i][j] = (f32x4){0.f, 0.f, 0.f, 0.f};

    short8 ra[2][4], rb[2][8];

#define LOADT2(kt2) do { \
    _Pragma("unroll") for (int ti = 0; ti < 4; ti++) { \
        ra[0][ti] = *(const short8*)&As[(size_t)ti * 8192 + soff + (kt2) * 128]; \
        ra[1][ti] = *(const short8*)&As[(size_t)ti * 8192 + soff + (kt2) * 128 + 64]; } \
    _Pragma("unroll") for (int ti = 0; ti < 8; ti++) { \
        rb[0][ti] = *(const short8*)&Bs[(size_t)ti * 8192 + soff + (kt2) * 128]; \
        rb[1][ti] = *(const short8*)&Bs[(size_t)ti * 8192 + soff + (kt2) * 128 + 64]; } \
} while (0)
#define WRITET2(cur) do { \
    _Pragma("unroll") for (int ti = 0; ti < 4; ti++) { \
        *(short8*)&Ab[cur][0][ti * 512 + ldst] = ra[0][ti]; \
        *(short8*)&Ab[cur][1][ti * 512 + ldst] = ra[1][ti]; } \
    _Pragma("unroll") for (int ti = 0; ti < 8; ti++) { \
        *(short8*)&Bb[cur][0][ti * 512 + ldst] = rb[0][ti]; \
        *(short8*)&Bb[cur][1][ti * 512 + ldst] = rb[1][ti]; } \
} while (0)

    const int frow = l & 15;
    const int fg = l >> 4;
    const int lx = l & 7;

    LOADT2(0);
    WRITET2(0);
    LOADT2(1);

    for (int tt = 0; tt < 8; ++tt) {
        const int cur = tt & 1;
        __syncthreads();
#pragma unroll
        for (int h = 0; h < 2; ++h)
#pragma unroll
            for (int ks = 0; ks < 2; ++ks) {
                const int ch = ((ks * 4 + fg) ^ lx) * 8;
                short8 af0 = *(const short8*)&Ab[cur][h][frow * 64 + ch];
                short8 af1 = *(const short8*)&Ab[cur][h][(16 + frow) * 64 + ch];
#pragma unroll
                for (int cg = 0; cg < 4; ++cg) {
                    short8 bf = *(const short8*)&Bb[cur][h][(cg * 16 + frow) * 64 + ch];
                    acc[0][cg] = __builtin_amdgcn_mfma_f32_16x16x32_bf16(af0, bf, acc[0][cg], 0, 0, 0);
                    acc[1][cg] = __builtin_amdgcn_mfma_f32_16x16x32_bf16(af1, bf, acc[1][cg], 0, 0, 0);
                }
            }
        if (tt < 7) {
            WRITET2(cur ^ 1);
            if (tt < 6) LOADT2(tt + 2);
        }
    }

    // head-major bf16 store: H[w][b][c][i][d], c = m>>3, d = m&7; V additionally transposed
    u16* dst = H + (size_t)w * 524288 + (size_t)b * 65536;
#pragma unroll
    for (int rg = 0; rg < 2; ++rg)
#pragma unroll
        for (int cg = 0; cg < 4; ++cg) {
            const int m = cg * 16 + frow;
            const int cc = m >> 3, d = m & 7;
#pragma unroll
            for (int r = 0; r < 4; ++r) {
                const int iq = it * 32 + rg * 16 + fg * 4 + r;
                const u16 val = f2bf(acc[rg][cg][r]);
                dst[((size_t)cc * L_SEQ + iq) * 8 + d] = val;
                if (w == 2)
                    VtG[((size_t)(b * 8 + cc) * 8 + d) * L_SEQ + iq] = val;
            }
        }
#undef LOADT2
#undef WRITET2
}

// ---------------- MFMA attention: block = (head, 64-query tile), 4 waves x 16-query strips ----------------
// S^T = mfma(A=K16, B=Q) with depth 8 zero-padded to 32; lane holds S^T[4g+r, q=l&15].
// P rebuilt to B-frag P^T[32k x 16q]: dest (qtil,g) needs keys 8g..8g+7 = half (g>>1 ? B : A)
// of source lanes g' = 2(g&1)+{0,1}. Shuffle BOTH halves, select by dest g.
// Causal predicate hoisted out of the first nfull=(base+1)>>5 chunks (fully active).
__global__ __launch_bounds__(256) void attn_mfma(
        const u16* __restrict__ H, const u16* __restrict__ VtG,
        const float* __restrict__ x, const float* __restrict__ pm,
        float* __restrict__ out) {
    const int qb = blockIdx.x;   // 16 query tiles of 64
    const int c  = blockIdx.y;   // 8
    const int b  = blockIdx.z;   // 8
    const int tid = threadIdx.x;
    const int wv = tid >> 6, lane = tid & 63;
    const int qtil = lane & 15, g = lane >> 4;

    __shared__ __align__(16) u16 Kl[8192];          // [1024 keys][8 d] bf16
    __shared__ __align__(16) u16 Vtl[8 * 1032];     // [8 d][1024+8 keys] bf16 (padded rows)

    const size_t hoff = (size_t)(b * 8 + c) * 8192;
    const u16* HQ = H + hoff;
    const u16* HK = H + 524288 + hoff;
    const int kend = (qb + 1) * 64;

    // stage K rows (bf16 copy)
    for (int k = tid; k < kend; k += 256)
        *(us8*)&Kl[k * 8] = *(const us8*)&HK[(size_t)k * 8];
    // stage V^T rows
    {
        const int vd = tid >> 5;                    // 0..7
        const u16* src = VtG + ((size_t)(b * 8 + c) * 8 + vd) * L_SEQ;
        for (int k8 = (tid & 31) * 8; k8 < kend; k8 += 256)
            *(us8*)&Vtl[vd * 1032 + k8] = *(const us8*)&src[k8];
    }

    // Q fragment (scaled, bf16), lanes g=0 carry d0..7, others zero-pad depth
    const int q = qb * 64 + wv * 16 + qtil;
    short8 qf = {0, 0, 0, 0, 0, 0, 0, 0};
    {
        us8 qv = *(const us8*)&HQ[(size_t)q * 8];
        if (g == 0) {
            const float sc = RS8 * LOG2E;
#pragma unroll
            for (int j = 0; j < 8; j++) qf[j] = (short)f2bf(bf2f(qv[j]) * sc);
        }
    }

    __syncthreads();

    const f32x4 czero = {0.f, 0.f, 0.f, 0.f};
    f32x4 oacc = czero;
    float lsum = 0.f;
    const short8 z8 = {0, 0, 0, 0, 0, 0, 0, 0};

#define ACHUNK(ch, PRED) do { \
    const int kb = (ch) * 32; \
    short8 kfA = z8, kfB = z8; \
    if (g == 0) { \
        kfA = *(const short8*)&Kl[(kb + qtil) * 8]; \
        kfB = *(const short8*)&Kl[(kb + 16 + qtil) * 8]; \
    } \
    f32x4 dA = __builtin_amdgcn_mfma_f32_16x16x32_bf16(kfA, qf, czero, 0, 0, 0); \
    f32x4 dB = __builtin_amdgcn_mfma_f32_16x16x32_bf16(kfB, qf, czero, 0, 0, 0); \
    float pA[4], pB[4]; \
    const int keyA = kb + 4 * g; \
    _Pragma("unroll") for (int r = 0; r < 4; r++) { \
        pA[r] = exp2f(dA[r]); \
        pB[r] = exp2f(dB[r]); \
        if (PRED) { \
            pA[r] = (keyA + r <= q) ? pA[r] : 0.f; \
            pB[r] = (keyA + 16 + r <= q) ? pB[r] : 0.f; \
        } \
        lsum += pA[r] + pB[r]; \
    } \
    const u32 A01 = cvtpk(pA[0], pA[1]), A23 = cvtpk(pA[2], pA[3]); \
    const u32 B01 = cvtpk(pB[0], pB[1]), B23 = cvtpk(pB[2], pB[3]); \
    const int src = qtil + ((g & 1) << 5); \
    const u32 a0 = (u32)__shfl((int)A01, src, 64); \
    const u32 a1 = (u32)__shfl((int)A23, src, 64); \
    const u32 a2 = (u32)__shfl((int)A01, src + 16, 64); \
    const u32 a3 = (u32)__shfl((int)A23, src + 16, 64); \
    const u32 b0 = (u32)__shfl((int)B01, src, 64); \
    const u32 b1 = (u32)__shfl((int)B23, src, 64); \
    const u32 b2 = (u32)__shfl((int)B01, src + 16, 64); \
    const u32 b3 = (u32)__shfl((int)B23, src + 16, 64); \
    union { u32 u[4]; short8 s; } pu; \
    pu.u[0] = (g < 2) ? a0 : b0; \
    pu.u[1] = (g < 2) ? a1 : b1; \
    pu.u[2] = (g < 2) ? a2 : b2; \
    pu.u[3] = (g < 2) ? a3 : b3; \
    short8 vf = z8; \
    if (qtil < 8) vf = *(const short8*)&Vtl[qtil * 1032 + kb + 8 * g]; \
    oacc = __builtin_amdgcn_mfma_f32_16x16x32_bf16(vf, pu.s, oacc, 0, 0, 0); \
} while (0)

    const int base = qb * 64 + wv * 16;    // min q in this wave
    const int nfull = (base + 1) >> 5;     // chunks with all 32 keys <= every lane's q
    const int nch = (base + 47) >> 5;      // all chunks this wave needs
    for (int ch = 0; ch < nfull; ++ch) ACHUNK(ch, false);
    for (int ch = nfull; ch < nch; ++ch) ACHUNK(ch, true);
#undef ACHUNK

    // total l per query (4 lanes share a query column)
    lsum += __shfl_xor(lsum, 16);
    lsum += __shfl_xor(lsum, 32);

    if (g < 2) {       // lane holds O[q][4g..4g+3]
        const float qm = pm[b * L_SEQ + q];
        const float r8 = qm / lsum;          // qm==0 -> out = x exactly
        const size_t off = (size_t)b * LM + (size_t)q * NM + c * 8 + g * 4;
        float4 xv = *(const float4*)&x[off];
        float4 o = make_float4(fmaf(oacc[0], r8, xv.x), fmaf(oacc[1], r8, xv.y),
                               fmaf(oacc[2], r8, xv.z), fmaf(oacc[3], r8, xv.w));
        *(float4*)&out[off] = o;
    }
}

// ---------------- Output 2: attention[b][k] = qm(b,1023)/8 * sum_c softmax_row_c[k] ----------------
__global__ __launch_bounds__(256) void out2_kernel(
        const u16* __restrict__ H, const float* __restrict__ pm,
        float* __restrict__ out2) {
    const int b = blockIdx.x;
    const int tid = threadIdx.x;
    const int lane = tid & 63, wv = tid >> 6;
    __shared__ float red[4];
    const float qm = pm[b * L_SEQ + 1023];
    const float sc = RS8 * LOG2E;
    float acc[4] = {0.f, 0.f, 0.f, 0.f};
    for (int cc = 0; cc < 8; cc++) {
        const size_t hoff = (size_t)(b * 8 + cc) * 8192;
        us8 qv = *(const us8*)&H[hoff + (size_t)1023 * 8];
        const float q0 = bf2f(qv[0]) * sc, q1 = bf2f(qv[1]) * sc;
        const float q2 = bf2f(qv[2]) * sc, q3 = bf2f(qv[3]) * sc;
        const float q4 = bf2f(qv[4]) * sc, q5 = bf2f(qv[5]) * sc;
        const float q6 = bf2f(qv[6]) * sc, q7 = bf2f(qv[7]) * sc;
        const u16* Kg = H + 524288 + hoff;
        float p[4];
        float ts = 0.f;
#pragma unroll
        for (int i = 0; i < 4; i++) {
            int k = tid + 256 * i;
            us8 kv = *(const us8*)&Kg[(size_t)k * 8];
            float sa = fmaf(q0, bf2f(kv[0]), fmaf(q1, bf2f(kv[1]), fmaf(q2, bf2f(kv[2]), q3 * bf2f(kv[3]))));
            float sb = fmaf(q4, bf2f(kv[4]), fmaf(q5, bf2f(kv[5]), fmaf(q6, bf2f(kv[6]), q7 * bf2f(kv[7]))));
            p[i] = exp2f(sa + sb);
            ts += p[i];
        }
        ts = wredsum(ts);
        if (lane == 0) red[wv] = ts;
        __syncthreads();
        const float inv = 0.125f / (red[0] + red[1] + red[2] + red[3]);
        __syncthreads();
#pragma unroll
        for (int i = 0; i < 4; i++) acc[i] = fmaf(p[i], inv, acc[i]);
    }
#pragma unroll
    for (int i = 0; i < 4; i++) out2[b * L_SEQ + tid + 256 * i] = acc[i] * qm;
}

extern "C" void kernel_launch(void* const* d_in, const int* in_sizes, int n_in,
                              void* d_out, int out_size, void* d_ws, size_t ws_size,
                              hipStream_t stream) {
    const float* x  = (const float*)d_in[0];
    const float* pm = (const float*)d_in[1];
    const float* Wq = (const float*)d_in[2];
    const float* Wk = (const float*)d_in[3];
    const float* Wv = (const float*)d_in[4];

    u16* H    = (u16*)d_ws;                              // 3 MB bf16 head-major Q,K,V
    u16* Wbf  = (u16*)((char*)d_ws + 3145728);           // 6 MB bf16 W[3][1024][1024]
    u16* xT   = (u16*)((char*)d_ws + 9437184);           // 1 MB bf16 xT[8][64][1024]
    u16* VtG  = (u16*)((char*)d_ws + 10485760);          // 1 MB bf16 Vt[64 heads][8][1024]
    float* out = (float*)d_out;                          // [8,1024,64] then [8,1024]

    hipLaunchKernelGGL(prep_kernel, dim3(1664), dim3(256), 0, stream, x, Wq, Wk, Wv, Wbf, xT);
    hipLaunchKernelGGL(proj_mfma, dim3(8, 32, 3), dim3(64), 0, stream, Wbf, xT, H, VtG);
    hipLaunchKernelGGL(attn_mfma, dim3(16, 8, 8), dim3(256), 0, stream, H, VtG, x, pm, out);
    hipLaunchKernelGGL(out2_kernel, dim3(8), dim3(256), 0, stream, H, pm, out + BLM);
}

// Round 12
// 50.834 us; speedup vs baseline: 1.3289x; 1.1414x over previous
//
#include <hip/hip_runtime.h>

#define L_SEQ 1024
#define NB 8
#define NM 64
#define LM (L_SEQ * NM)    // 65536
#define BLM (NB * LM)      // 524288
#define RS8 0.35355339059327373f
#define LOG2E 1.4426950408889634f

typedef unsigned short u16;
typedef unsigned int u32;
typedef __attribute__((ext_vector_type(8))) short short8;
typedef __attribute__((ext_vector_type(4))) float f32x4;
typedef __attribute__((ext_vector_type(8))) u16 us8;

__device__ __forceinline__ float wredsum(float v) {
#pragma unroll
    for (int off = 32; off; off >>= 1) v += __shfl_xor(v, off);
    return v;
}

__device__ __forceinline__ u16 f2bf(float f) {
    u32 u = __float_as_uint(f);
    u32 r = (u + 0x7FFFu + ((u >> 16) & 1u)) >> 16;
    return (u16)r;
}
__device__ __forceinline__ float bf2f(u16 u) {
    return __uint_as_float((u32)u << 16);
}
// packed RNE f32->bf16 pair (1 VALU op)
__device__ __forceinline__ u32 cvtpk(float lo, float hi) {
    u32 r;
    asm("v_cvt_pk_bf16_f32 %0, %1, %2" : "=v"(r) : "v"(lo), "v"(hi));
    return r;
}

// ---------------- Prep: W fp32 -> bf16 (same layout); x[b][k][m] -> xT[b][m][k] bf16 ----------------
__global__ __launch_bounds__(256) void prep_kernel(
        const float* __restrict__ x, const float* __restrict__ Wq,
        const float* __restrict__ Wk, const float* __restrict__ Wv,
        u16* __restrict__ Wbf, u16* __restrict__ xT) {
    const int bx = blockIdx.x;
    const int tid = threadIdx.x;
    if (bx < 1536) {                       // W convert: 3 x 512 blocks x 2048 elements
        const int w = bx >> 9;
        const int blk = bx & 511;
        const float* W = (w == 0) ? Wq : (w == 1) ? Wk : Wv;
        const size_t base = (size_t)blk * 2048 + (size_t)tid * 8;
        float4 f0 = *(const float4*)&W[base];
        float4 f1 = *(const float4*)&W[base + 4];
        us8 o;
        o[0] = f2bf(f0.x); o[1] = f2bf(f0.y); o[2] = f2bf(f0.z); o[3] = f2bf(f0.w);
        o[4] = f2bf(f1.x); o[5] = f2bf(f1.y); o[6] = f2bf(f1.z); o[7] = f2bf(f1.w);
        *(us8*)&Wbf[(size_t)w * 1048576 + base] = o;
    } else {                               // x transpose: 128 blocks (b, ktile)
        const int blk = bx - 1536;
        const int b = blk >> 4, kt = blk & 15;
        __shared__ float T[64][65];
        const int r16 = tid >> 4, c4 = (tid & 15) * 4;
#pragma unroll
        for (int s = 0; s < 4; s++) {
            int r = r16 + s * 16;
            *(float4*)&T[r][c4] = *(const float4*)&x[((size_t)b * L_SEQ + kt * 64 + r) * NM + c4];
        }
        __syncthreads();
        const int m = tid >> 2;
#pragma unroll
        for (int s = 0; s < 2; s++) {
            int c = (tid & 3) * 2 + s;
            int k0 = c * 8;
            us8 o;
#pragma unroll
            for (int j = 0; j < 8; j++) o[j] = f2bf(T[k0 + j][m]);
            *(us8*)&xT[((size_t)b * NM + m) * L_SEQ + kt * 64 + k0] = o;
        }
    }
}

// ---------------- Projection via MFMA -> head-major bf16 H[w][b][c][seq][8]; V also transposed ----------------
// BK=64, 24 KB LDS (6 blocks/CU — BK=128's 48 KB halved occupancy, guide m132). b-fastest grid.
__global__ __launch_bounds__(64) void proj_mfma(
        const u16* __restrict__ Wbf, const u16* __restrict__ xT,
        u16* __restrict__ H, u16* __restrict__ VtG) {
    const int b  = blockIdx.x;   // 8 (fastest: consecutive blocks share the W tile in L2)
    const int it = blockIdx.y;   // 32 row tiles
    const int w  = blockIdx.z;   // 3
    const int l  = threadIdx.x;

    __shared__ __align__(16) u16 Ab[2][2048];   // [32 rows][64 k] swizzled
    __shared__ __align__(16) u16 Bb[2][4096];   // [64 m][64 k] swizzled

    const u16* As = Wbf + (size_t)w * 1048576 + (size_t)(it * 32) * L_SEQ;
    const u16* Bs = xT + (size_t)b * (NM * L_SEQ);

    const int soff = (l >> 3) * L_SEQ + (((l & 7) ^ (l >> 3)) * 8);
    const int ldst = l * 8;

    f32x4 acc[2][4];
#pragma unroll
    for (int i = 0; i < 2; i++)
#pragma unroll
        for (int j = 0; j < 4; j++) acc[i][j] = (f32x4){0.f, 0.f, 0.f, 0.f};

    short8 ra[4], rb[8];

#define LOADT(kt)  do { \
    _Pragma("unroll") for (int ti = 0; ti < 4; ti++) ra[ti] = *(const short8*)&As[(size_t)ti * 8192 + soff + (kt) * 64]; \
    _Pragma("unroll") for (int ti = 0; ti < 8; ti++) rb[ti] = *(const short8*)&Bs[(size_t)ti * 8192 + soff + (kt) * 64]; \
} while (0)
#define WRITET(cur) do { \
    _Pragma("unroll") for (int ti = 0; ti < 4; ti++) *(short8*)&Ab[cur][ti * 512 + ldst] = ra[ti]; \
    _Pragma("unroll") for (int ti = 0; ti < 8; ti++) *(short8*)&Bb[cur][ti * 512 + ldst] = rb[ti]; \
} while (0)

    const int frow = l & 15;
    const int fg = l >> 4;
    const int lx = l & 7;

    LOADT(0);
    WRITET(0);
    LOADT(1);

    for (int kt = 0; kt < 16; ++kt) {
        const int cur = kt & 1;
        __syncthreads();
#pragma unroll
        for (int ks = 0; ks < 2; ++ks) {
            const int ch = ((ks * 4 + fg) ^ lx) * 8;
            short8 af0 = *(const short8*)&Ab[cur][frow * 64 + ch];
            short8 af1 = *(const short8*)&Ab[cur][(16 + frow) * 64 + ch];
#pragma unroll
            for (int cg = 0; cg < 4; ++cg) {
                short8 bf = *(const short8*)&Bb[cur][(cg * 16 + frow) * 64 + ch];
                acc[0][cg] = __builtin_amdgcn_mfma_f32_16x16x32_bf16(af0, bf, acc[0][cg], 0, 0, 0);
                acc[1][cg] = __builtin_amdgcn_mfma_f32_16x16x32_bf16(af1, bf, acc[1][cg], 0, 0, 0);
            }
        }
        if (kt < 15) {
            WRITET(cur ^ 1);
            if (kt < 14) LOADT(kt + 2);
        }
    }

    // head-major bf16 store: H[w][b][c][i][d], c = m>>3, d = m&7; V additionally transposed
    u16* dst = H + (size_t)w * 524288 + (size_t)b * 65536;
#pragma unroll
    for (int rg = 0; rg < 2; ++rg)
#pragma unroll
        for (int cg = 0; cg < 4; ++cg) {
            const int m = cg * 16 + frow;
            const int cc = m >> 3, d = m & 7;
#pragma unroll
            for (int r = 0; r < 4; ++r) {
                const int iq = it * 32 + rg * 16 + fg * 4 + r;
                const u16 val = f2bf(acc[rg][cg][r]);
                dst[((size_t)cc * L_SEQ + iq) * 8 + d] = val;
                if (w == 2)
                    VtG[((size_t)(b * 8 + cc) * 8 + d) * L_SEQ + iq] = val;
            }
        }
#undef LOADT
#undef WRITET
}

// ---------------- MFMA attention, causal-pair-balanced ----------------
// Block (s,c,b), s=0..7: handles query tiles qlo=s and qhi=15-s sequentially per wave.
// Per-wave chunk total = 32..34 for EVERY wave of EVERY block (uniform, no tail).
// S^T = mfma(A=K16, B=Q) (d=8 zero-padded); P^T rebuilt via 8 shfl (select by dest g).
__global__ __launch_bounds__(256) void attn_mfma(
        const u16* __restrict__ H, const u16* __restrict__ VtG,
        const float* __restrict__ x, const float* __restrict__ pm,
        float* __restrict__ out) {
    const int s = blockIdx.x;    // 8 tile pairs
    const int c = blockIdx.y;    // 8
    const int b = blockIdx.z;    // 8
    const int tid = threadIdx.x;
    const int wv = tid >> 6, lane = tid & 63;
    const int qtil = lane & 15, g = lane >> 4;

    __shared__ __align__(16) u16 Kl[8192];          // [1024 keys][8 d] bf16
    __shared__ __align__(16) u16 Vtl[8 * 1032];     // [8 d][1024+8 keys] bf16 (padded rows)

    const size_t hoff = (size_t)(b * 8 + c) * 8192;
    const u16* HQ = H + hoff;
    const u16* HK = H + 524288 + hoff;
    const int qlo = s, qhi = 15 - s;
    const int kend = (qhi + 1) * 64;     // superset: covers both tiles' needs

    // stage K rows (bf16 copy)
    for (int k = tid; k < kend; k += 256)
        *(us8*)&Kl[k * 8] = *(const us8*)&HK[(size_t)k * 8];
    // stage V^T rows
    {
        const int vd = tid >> 5;                    // 0..7
        const u16* src = VtG + ((size_t)(b * 8 + c) * 8 + vd) * L_SEQ;
        for (int k8 = (tid & 31) * 8; k8 < kend; k8 += 256)
            *(us8*)&Vtl[vd * 1032 + k8] = *(const us8*)&src[k8];
    }

    // Q fragments for both tiles (scaled bf16; g=0 lanes carry data, others zero-pad depth)
    short8 qfLo = {0, 0, 0, 0, 0, 0, 0, 0};
    short8 qfHi = {0, 0, 0, 0, 0, 0, 0, 0};
    {
        const float sc = RS8 * LOG2E;
        us8 qvLo = *(const us8*)&HQ[(size_t)(qlo * 64 + wv * 16 + qtil) * 8];
        us8 qvHi = *(const us8*)&HQ[(size_t)(qhi * 64 + wv * 16 + qtil) * 8];
        if (g == 0) {
#pragma unroll
            for (int j = 0; j < 8; j++) {
                qfLo[j] = (short)f2bf(bf2f(qvLo[j]) * sc);
                qfHi[j] = (short)f2bf(bf2f(qvHi[j]) * sc);
            }
        }
    }

    __syncthreads();

    const f32x4 czero = {0.f, 0.f, 0.f, 0.f};
    const short8 z8 = {0, 0, 0, 0, 0, 0, 0, 0};

#define ACHUNK2(QF, ch, PRED) do { \
    const int kb_ = (ch) * 32; \
    short8 kfA_ = z8, kfB_ = z8; \
    if (g == 0) { \
        kfA_ = *(const short8*)&Kl[(kb_ + qtil) * 8]; \
        kfB_ = *(const short8*)&Kl[(kb_ + 16 + qtil) * 8]; \
    } \
    f32x4 dA_ = __builtin_amdgcn_mfma_f32_16x16x32_bf16(kfA_, QF, czero, 0, 0, 0); \
    f32x4 dB_ = __builtin_amdgcn_mfma_f32_16x16x32_bf16(kfB_, QF, czero, 0, 0, 0); \
    float pA_[4], pB_[4]; \
    const int keyA_ = kb_ + 4 * g; \
    _Pragma("unroll") for (int r_ = 0; r_ < 4; r_++) { \
        pA_[r_] = exp2f(dA_[r_]); \
        pB_[r_] = exp2f(dB_[r_]); \
        if (PRED) { \
            pA_[r_] = (keyA_ + r_ <= q_) ? pA_[r_] : 0.f; \
            pB_[r_] = (keyA_ + 16 + r_ <= q_) ? pB_[r_] : 0.f; \
        } \
        lsum_ += pA_[r_] + pB_[r_]; \
    } \
    const u32 A01_ = cvtpk(pA_[0], pA_[1]), A23_ = cvtpk(pA_[2], pA_[3]); \
    const u32 B01_ = cvtpk(pB_[0], pB_[1]), B23_ = cvtpk(pB_[2], pB_[3]); \
    const int src_ = qtil + ((g & 1) << 5); \
    const u32 a0_ = (u32)__shfl((int)A01_, src_, 64); \
    const u32 a1_ = (u32)__shfl((int)A23_, src_, 64); \
    const u32 a2_ = (u32)__shfl((int)A01_, src_ + 16, 64); \
    const u32 a3_ = (u32)__shfl((int)A23_, src_ + 16, 64); \
    const u32 b0_ = (u32)__shfl((int)B01_, src_, 64); \
    const u32 b1_ = (u32)__shfl((int)B23_, src_, 64); \
    const u32 b2_ = (u32)__shfl((int)B01_, src_ + 16, 64); \
    const u32 b3_ = (u32)__shfl((int)B23_, src_ + 16, 64); \
    union { u32 u[4]; short8 s; } pu_; \
    pu_.u[0] = (g < 2) ? a0_ : b0_; \
    pu_.u[1] = (g < 2) ? a1_ : b1_; \
    pu_.u[2] = (g < 2) ? a2_ : b2_; \
    pu_.u[3] = (g < 2) ? a3_ : b3_; \
    short8 vf_ = z8; \
    if (qtil < 8) vf_ = *(const short8*)&Vtl[qtil * 1032 + kb_ + 8 * g]; \
    oacc_ = __builtin_amdgcn_mfma_f32_16x16x32_bf16(vf_, pu_.s, oacc_, 0, 0, 0); \
} while (0)

#define RUNPASS(QF, TILE) do { \
    const int base_ = (TILE) * 64 + wv * 16; \
    const int q_ = base_ + qtil; \
    f32x4 oacc_ = czero; \
    float lsum_ = 0.f; \
    const int nfull_ = (base_ + 1) >> 5; \
    const int nch_ = (base_ + 47) >> 5; \
    for (int ch_ = 0; ch_ < nfull_; ++ch_) ACHUNK2(QF, ch_, false); \
    for (int ch_ = nfull_; ch_ < nch_; ++ch_) ACHUNK2(QF, ch_, true); \
    lsum_ += __shfl_xor(lsum_, 16); \
    lsum_ += __shfl_xor(lsum_, 32); \
    if (g < 2) { \
        const float qm_ = pm[b * L_SEQ + q_]; \
        const float r8_ = qm_ / lsum_; \
        const size_t off_ = (size_t)b * LM + (size_t)q_ * NM + c * 8 + g * 4; \
        float4 xv_ = *(const float4*)&x[off_]; \
        float4 o_ = make_float4(fmaf(oacc_[0], r8_, xv_.x), fmaf(oacc_[1], r8_, xv_.y), \
                                fmaf(oacc_[2], r8_, xv_.z), fmaf(oacc_[3], r8_, xv_.w)); \
        *(float4*)&out[off_] = o_; \
    } \
} while (0)

    RUNPASS(qfLo, qlo);
    RUNPASS(qfHi, qhi);
#undef RUNPASS
#undef ACHUNK2
}

// ---------------- Output 2: attention[b][k] = qm(b,1023)/8 * sum_c softmax_row_c[k] ----------------
__global__ __launch_bounds__(256) void out2_kernel(
        const u16* __restrict__ H, const float* __restrict__ pm,
        float* __restrict__ out2) {
    const int b = blockIdx.x;
    const int tid = threadIdx.x;
    const int lane = tid & 63, wv = tid >> 6;
    __shared__ float red[4];
    const float qm = pm[b * L_SEQ + 1023];
    const float sc = RS8 * LOG2E;
    float acc[4] = {0.f, 0.f, 0.f, 0.f};
    for (int cc = 0; cc < 8; cc++) {
        const size_t hoff = (size_t)(b * 8 + cc) * 8192;
        us8 qv = *(const us8*)&H[hoff + (size_t)1023 * 8];
        const float q0 = bf2f(qv[0]) * sc, q1 = bf2f(qv[1]) * sc;
        const float q2 = bf2f(qv[2]) * sc, q3 = bf2f(qv[3]) * sc;
        const float q4 = bf2f(qv[4]) * sc, q5 = bf2f(qv[5]) * sc;
        const float q6 = bf2f(qv[6]) * sc, q7 = bf2f(qv[7]) * sc;
        const u16* Kg = H + 524288 + hoff;
        float p[4];
        float ts = 0.f;
#pragma unroll
        for (int i = 0; i < 4; i++) {
            int k = tid + 256 * i;
            us8 kv = *(const us8*)&Kg[(size_t)k * 8];
            float sa = fmaf(q0, bf2f(kv[0]), fmaf(q1, bf2f(kv[1]), fmaf(q2, bf2f(kv[2]), q3 * bf2f(kv[3]))));
            float sb = fmaf(q4, bf2f(kv[4]), fmaf(q5, bf2f(kv[5]), fmaf(q6, bf2f(kv[6]), q7 * bf2f(kv[7]))));
            p[i] = exp2f(sa + sb);
            ts += p[i];
        }
        ts = wredsum(ts);
        if (lane == 0) red[wv] = ts;
        __syncthreads();
        const float inv = 0.125f / (red[0] + red[1] + red[2] + red[3]);
        __syncthreads();
#pragma unroll
        for (int i = 0; i < 4; i++) acc[i] = fmaf(p[i], inv, acc[i]);
    }
#pragma unroll
    for (int i = 0; i < 4; i++) out2[b * L_SEQ + tid + 256 * i] = acc[i] * qm;
}

extern "C" void kernel_launch(void* const* d_in, const int* in_sizes, int n_in,
                              void* d_out, int out_size, void* d_ws, size_t ws_size,
                              hipStream_t stream) {
    const float* x  = (const float*)d_in[0];
    const float* pm = (const float*)d_in[1];
    const float* Wq = (const float*)d_in[2];
    const float* Wk = (const float*)d_in[3];
    const float* Wv = (const float*)d_in[4];

    u16* H    = (u16*)d_ws;                              // 3 MB bf16 head-major Q,K,V
    u16* Wbf  = (u16*)((char*)d_ws + 3145728);           // 6 MB bf16 W[3][1024][1024]
    u16* xT   = (u16*)((char*)d_ws + 9437184);           // 1 MB bf16 xT[8][64][1024]
    u16* VtG  = (u16*)((char*)d_ws + 10485760);          // 1 MB bf16 Vt[64 heads][8][1024]
    float* out = (float*)d_out;                          // [8,1024,64] then [8,1024]

    hipLaunchKernelGGL(prep_kernel, dim3(1664), dim3(256), 0, stream, x, Wq, Wk, Wv, Wbf, xT);
    hipLaunchKernelGGL(proj_mfma, dim3(8, 32, 3), dim3(64), 0, stream, Wbf, xT, H, VtG);
    hipLaunchKernelGGL(attn_mfma, dim3(8, 8, 8), dim3(256), 0, stream, H, VtG, x, pm, out);
    hipLaunchKernelGGL(out2_kernel, dim3(8), dim3(256), 0, stream, H, pm, out + BLM);
}